// Round 1
// baseline (139151.440 us; speedup 1.0000x reference)
//
#include <hip/hip_runtime.h>
#include <hip/hip_bf16.h>
#include <math.h>

// GRU: B=64, T=512, D=512, H=1024, fp32.
// Round 0: correctness-first fp32 baseline.
//   - 512 sequential step-kernel launches (kernel boundary = device barrier)
//   - x-projection fused into each step (no big workspace needed)
//   - h double-buffered in ws (2 x 256 KB); last step writes d_out directly
#define Bb 64
#define Tt 512
#define Dd 512
#define Hh 1024
#define BN 8      // output columns per block
#define BK 128    // K chunk staged in LDS
#define PAD 129   // 128+1: lane stride (b*129+k)%32 covers all banks, 2-way = free

__device__ __forceinline__ float fast_sigmoid(float x) {
    return 1.0f / (1.0f + __expf(-x));
}
__device__ __forceinline__ float fast_tanh(float x) {
    // tanh(x) = 1 - 2/(exp(2x)+1); stable at both extremes (exp->inf => 1, exp->0 => -1)
    return 1.0f - 2.0f / (__expf(2.0f * x) + 1.0f);
}

__global__ __launch_bounds__(512) void gru_step(
    const float* __restrict__ x, int t,
    const float* __restrict__ Wzx, const float* __restrict__ Wzh,
    const float* __restrict__ Wrx, const float* __restrict__ Wrh,
    const float* __restrict__ Wnx, const float* __restrict__ Wnh,
    const float* __restrict__ bzx, const float* __restrict__ bzh,
    const float* __restrict__ brx, const float* __restrict__ brh,
    const float* __restrict__ bnx, const float* __restrict__ bnh,
    const float* __restrict__ hin, float* __restrict__ hout)
{
    __shared__ float a_lds[Bb * PAD];   // 64 x 129 fp32 = 33 KB

    const int tid = threadIdx.x;
    const int b   = tid & 63;           // row (batch)
    const int jj  = tid >> 6;           // 0..7 -> wave id == jj (W addr wave-uniform)
    const int j   = blockIdx.x * BN + jj;

    float acc_z = 0.f, acc_r = 0.f, acc_u = 0.f, acc_v = 0.f;

    // ---------------- x-side: K = D = 512 ----------------
    for (int d0 = 0; d0 < Dd; d0 += BK) {
        __syncthreads();   // protect previous chunk's readers
        // stage x[b, t, d0..d0+127] -> a_lds[b][0..127]; 8192 floats / 512 thr = 4 float4 each
        #pragma unroll
        for (int i = 0; i < 4; ++i) {
            int f   = i * 512 + tid;        // float4 index, 32 per row
            int row = f >> 5;
            int c4  = (f & 31) << 2;
            const float4 v = *(const float4*)(x + ((size_t)row * Tt + t) * Dd + d0 + c4);
            float* dst = &a_lds[row * PAD + c4];
            dst[0] = v.x; dst[1] = v.y; dst[2] = v.z; dst[3] = v.w;
        }
        __syncthreads();
        const float* wz = Wzx + (size_t)d0 * Hh + j;
        const float* wr = Wrx + (size_t)d0 * Hh + j;
        const float* wn = Wnx + (size_t)d0 * Hh + j;
        const float* al = &a_lds[b * PAD];
        #pragma unroll 8
        for (int k = 0; k < BK; ++k) {
            float av = al[k];
            acc_z += av * wz[(size_t)k * Hh];
            acc_r += av * wr[(size_t)k * Hh];
            acc_u += av * wn[(size_t)k * Hh];
        }
    }

    // ---------------- h-side: K = H = 1024 ----------------
    for (int k0 = 0; k0 < Hh; k0 += BK) {
        __syncthreads();
        #pragma unroll
        for (int i = 0; i < 4; ++i) {
            int f   = i * 512 + tid;
            int row = f >> 5;
            int c4  = (f & 31) << 2;
            const float4 v = *(const float4*)(hin + (size_t)row * Hh + k0 + c4);
            float* dst = &a_lds[row * PAD + c4];
            dst[0] = v.x; dst[1] = v.y; dst[2] = v.z; dst[3] = v.w;
        }
        __syncthreads();
        const float* wz = Wzh + (size_t)k0 * Hh + j;
        const float* wr = Wrh + (size_t)k0 * Hh + j;
        const float* wn = Wnh + (size_t)k0 * Hh + j;
        const float* al = &a_lds[b * PAD];
        #pragma unroll 8
        for (int k = 0; k < BK; ++k) {
            float av = al[k];
            acc_z += av * wz[(size_t)k * Hh];
            acc_r += av * wr[(size_t)k * Hh];
            acc_v += av * wn[(size_t)k * Hh];
        }
    }

    // ---------------- epilogue ----------------
    float z = fast_sigmoid(acc_z + bzx[j] + bzh[j]);
    float r = fast_sigmoid(acc_r + brx[j] + brh[j]);
    float u = acc_u + bnx[j];                  // x-side n pre-act (bias outside r-gate)
    float v = acc_v + bnh[j];                  // h-side n pre-act (bias inside r-gate)
    float n = fast_tanh(u + r * v);
    float hp = hin[(size_t)b * Hh + j];
    hout[(size_t)b * Hh + j] = (1.0f - z) * n + z * hp;
}

__global__ void zero_kernel(float* __restrict__ p, int n) {
    int i = blockIdx.x * blockDim.x + threadIdx.x;
    if (i < n) p[i] = 0.0f;
}

extern "C" void kernel_launch(void* const* d_in, const int* in_sizes, int n_in,
                              void* d_out, int out_size, void* d_ws, size_t ws_size,
                              hipStream_t stream) {
    const float* x   = (const float*)d_in[0];
    const float* Wzx = (const float*)d_in[1];
    const float* Wzh = (const float*)d_in[2];
    const float* Wrx = (const float*)d_in[3];
    const float* Wrh = (const float*)d_in[4];
    const float* Wnx = (const float*)d_in[5];
    const float* Wnh = (const float*)d_in[6];
    const float* bzx = (const float*)d_in[7];
    const float* bzh = (const float*)d_in[8];
    const float* brx = (const float*)d_in[9];
    const float* brh = (const float*)d_in[10];
    const float* bnx = (const float*)d_in[11];
    const float* bnh = (const float*)d_in[12];

    float* hA = (float*)d_ws;        // [64*1024]
    float* hB = hA + Bb * Hh;

    // ws is poisoned 0xAA before every call: zero the initial h buffer.
    zero_kernel<<<(Bb * Hh + 255) / 256, 256, 0, stream>>>(hA, Bb * Hh);

    for (int t = 0; t < Tt; ++t) {
        const float* hin = (t & 1) ? hB : hA;
        float* hout = (t == Tt - 1) ? (float*)d_out : ((t & 1) ? hA : hB);
        gru_step<<<Hh / BN, 512, 0, stream>>>(x, t,
                                              Wzx, Wzh, Wrx, Wrh, Wnx, Wnh,
                                              bzx, bzh, brx, brh, bnx, bnh,
                                              hin, hout);
    }
}

// Round 2
// 34994.598 us; speedup vs baseline: 3.9764x; 3.9764x over previous
//
#include <hip/hip_runtime.h>
#include <math.h>

// GRU B=64, T=512, D=512, H=1024 fp32.
// Round 1: persistent kernel, split-bf16 MFMA, K-split 12 x N-split 16 = 192 blocks,
// two-phase step (partial GEMM -> grid barrier -> reduce+gates -> grid barrier).
#define T_STEPS 512
#define Bb 64
#define Dd 512
#define Hh 1024
#define NBLK 192
#define KP_X 4          // kp 0..3 = x-side (k = kp*128), kp 4..11 = h-side
#define KP_TOT 12
#define NCT 16
#define LDS_STRIDE 136  // shorts per row: 128 + 8 pad (row stride 272B -> 2-way bank alias, free)
#define EPB 342         // epilogue elements per block (192*342 >= 65536)

typedef __attribute__((ext_vector_type(8))) short short8;
typedef __attribute__((ext_vector_type(4))) short short4v;
typedef __attribute__((ext_vector_type(4))) float floatx4;

__device__ __forceinline__ unsigned short f2bf(float f) {
    unsigned u = __float_as_uint(f);
    unsigned r = u + 0x7fffu + ((u >> 16) & 1u);   // round-to-nearest-even
    return (unsigned short)(r >> 16);
}
__device__ __forceinline__ float bf2f(unsigned short h) {
    return __uint_as_float(((unsigned)h) << 16);
}

// ---------------- setup: split W into hi/lo bf16, swizzled into MFMA B-fragment order ----
// layout: frag(ct,ks,g,s) = 512 shorts; element: lane l, j -> B[k=ks*32+(l>>4)*8+j][n=ct*16+(l&15)]
__global__ __launch_bounds__(256) void build_wsw(
    const float* __restrict__ Wzx, const float* __restrict__ Wzh,
    const float* __restrict__ Wrx, const float* __restrict__ Wrh,
    const float* __restrict__ Wnx, const float* __restrict__ Wnh,
    unsigned short* __restrict__ wsw)
{
    int idx = blockIdx.x * 256 + threadIdx.x;   // 589824 total = 2304*256
    int l = idx & 63;
    int rest = idx >> 6;
    int g = rest % 3; rest /= 3;
    int ks = rest % 48;
    int ct = rest / 48;
    if (ct >= 64) return;
    int k0 = ks * 32 + ((l >> 4) << 3);
    int n  = ct * 16 + (l & 15);
    const float* Wx = (g == 0) ? Wzx : (g == 1) ? Wrx : Wnx;
    const float* Wh = (g == 0) ? Wzh : (g == 1) ? Wrh : Wnh;
    const float* src = (k0 < Dd) ? (Wx + (size_t)k0 * Hh + n)
                                 : (Wh + (size_t)(k0 - Dd) * Hh + n);
    size_t base = ((((size_t)ct * 48 + ks) * 3 + g) * 2) * 512;
    unsigned short* hi = wsw + base + l * 8;
    unsigned short* lo = hi + 512;
    #pragma unroll
    for (int j = 0; j < 8; ++j) {
        float w = src[(size_t)j * Hh];
        unsigned short h16 = f2bf(w);
        hi[j] = h16;
        lo[j] = f2bf(w - bf2f(h16));
    }
}

// ---------------- two-level grid barrier (8 groups x 24 blocks), monotonic phases ----------
__device__ __forceinline__ void grid_barrier(unsigned* bar, int phase, int gid, int tid) {
    __syncthreads();
    if (tid == 0) {
        __threadfence();   // device-scope release of this block's stores
        unsigned old = __hip_atomic_fetch_add(&bar[gid * 16], 1u,
                                              __ATOMIC_ACQ_REL, __HIP_MEMORY_SCOPE_AGENT);
        if (old == (unsigned)(phase * 24 + 23)) {            // last arriver in group
            unsigned m = __hip_atomic_fetch_add(&bar[128], 1u,
                                                __ATOMIC_ACQ_REL, __HIP_MEMORY_SCOPE_AGENT);
            if (m == (unsigned)(phase * 8 + 7)) {            // last group
                __hip_atomic_fetch_add(&bar[144], 1u,
                                       __ATOMIC_RELEASE, __HIP_MEMORY_SCOPE_AGENT);
            }
        }
        while (__hip_atomic_load(&bar[144], __ATOMIC_ACQUIRE,
                                 __HIP_MEMORY_SCOPE_AGENT) < (unsigned)(phase + 1)) {
            __builtin_amdgcn_s_sleep(2);
        }
    }
    __syncthreads();
}

// ---------------- persistent GRU kernel ----------------
__global__ __launch_bounds__(256) void gru_persist(
    const float* __restrict__ x,
    const float* __restrict__ bzx, const float* __restrict__ bzh,
    const float* __restrict__ brx, const float* __restrict__ brh,
    const float* __restrict__ bnx, const float* __restrict__ bnh,
    const unsigned short* __restrict__ wsw,
    unsigned short* __restrict__ hb0, unsigned short* __restrict__ hb1,
    float* __restrict__ Pz, float* __restrict__ Pr, float* __restrict__ Pn,
    unsigned* __restrict__ bar,
    float* __restrict__ out)
{
    __shared__ unsigned short lds_a[Bb * LDS_STRIDE];   // 17.4 KB

    const int tid  = threadIdx.x;
    const int lane = tid & 63;
    const int wave = tid >> 6;
    const int kp   = blockIdx.x / NCT;    // 0..11 (K partition)
    const int ct4  = blockIdx.x % NCT;    // 0..15 (64-col slice)
    const int ct   = ct4 * 4 + wave;      // 16-col tile per wave
    const int gid  = blockIdx.x / 24;     // barrier group

    // ---- fixed epilogue assignment: 2 elements per thread, constant across all steps ----
    const int e_base = blockIdx.x * EPB;
    int  ee[2];  bool vv[2];
    ee[0] = e_base + tid;         vv[0] = (ee[0] < Bb * Hh);
    ee[1] = e_base + 256 + tid;   vv[1] = (tid < EPB - 256) && (ee[1] < Bb * Hh);
    float bzs[2], brs[2], bus[2], bvs[2], hp[2];
    #pragma unroll
    for (int q = 0; q < 2; ++q) {
        bzs[q] = brs[q] = bus[q] = bvs[q] = 0.f; hp[q] = 0.f;
        if (vv[q]) {
            int j = ee[q] & (Hh - 1);
            bzs[q] = bzx[j] + bzh[j];
            brs[q] = brx[j] + brh[j];
            bus[q] = bnx[j];
            bvs[q] = bnh[j];
        }
    }

    const size_t wbase = (((size_t)ct * 48 + kp * 4) * 3) * 2 * 512 + (size_t)lane * 8;

    for (int t = 0; t < T_STEPS; ++t) {
        const unsigned short* hin  = (t & 1) ? hb1 : hb0;
        unsigned short*       hout = (t & 1) ? hb0 : hb1;

        // ---------- phase 1a: stage A slice [64 rows x 128 k] into LDS ----------
        if (kp < KP_X) {
            #pragma unroll
            for (int i = 0; i < 8; ++i) {
                int flat = i * 256 + tid;       // 2048 x 16B fp32 chunks
                int row = flat >> 5;
                int c   = flat & 31;
                float4 v4 = *(const float4*)(x + ((size_t)row * T_STEPS + t) * Dd
                                             + kp * 128 + c * 4);
                short4v s;
                s.x = (short)f2bf(v4.x); s.y = (short)f2bf(v4.y);
                s.z = (short)f2bf(v4.z); s.w = (short)f2bf(v4.w);
                *(short4v*)&lds_a[row * LDS_STRIDE + c * 4] = s;
            }
        } else {
            #pragma unroll
            for (int i = 0; i < 4; ++i) {
                int flat = i * 256 + tid;       // 1024 x 16B bf16 chunks
                int row = flat >> 4;
                int c   = flat & 15;
                short8 v8 = *(const short8*)(hin + (size_t)row * Hh
                                             + (kp - KP_X) * 128 + c * 8);
                *(short8*)&lds_a[row * LDS_STRIDE + c * 8] = v8;
            }
        }
        __syncthreads();

        // ---------- phase 1b: MFMA partial GEMM (W streamed, split hi+lo) ----------
        floatx4 zero4 = {0.f, 0.f, 0.f, 0.f};
        floatx4 accZ[4] = {zero4, zero4, zero4, zero4};
        floatx4 accR[4] = {zero4, zero4, zero4, zero4};
        floatx4 accN[4] = {zero4, zero4, zero4, zero4};
        #pragma unroll
        for (int ks = 0; ks < 4; ++ks) {
            const unsigned short* wp = wsw + wbase + (size_t)ks * 3072;
            short8 bzh8 = *(const short8*)(wp);
            short8 bzl8 = *(const short8*)(wp + 512);
            short8 brh8 = *(const short8*)(wp + 1024);
            short8 brl8 = *(const short8*)(wp + 1536);
            short8 bnh8 = *(const short8*)(wp + 2048);
            short8 bnl8 = *(const short8*)(wp + 2560);
            #pragma unroll
            for (int m = 0; m < 4; ++m) {
                const short8 a = *(const short8*)&lds_a[(m * 16 + (lane & 15)) * LDS_STRIDE
                                                        + ks * 32 + ((lane >> 4) << 3)];
                accZ[m] = __builtin_amdgcn_mfma_f32_16x16x32_bf16(a, bzh8, accZ[m], 0, 0, 0);
                accZ[m] = __builtin_amdgcn_mfma_f32_16x16x32_bf16(a, bzl8, accZ[m], 0, 0, 0);
                accR[m] = __builtin_amdgcn_mfma_f32_16x16x32_bf16(a, brh8, accR[m], 0, 0, 0);
                accR[m] = __builtin_amdgcn_mfma_f32_16x16x32_bf16(a, brl8, accR[m], 0, 0, 0);
                accN[m] = __builtin_amdgcn_mfma_f32_16x16x32_bf16(a, bnh8, accN[m], 0, 0, 0);
                accN[m] = __builtin_amdgcn_mfma_f32_16x16x32_bf16(a, bnl8, accN[m], 0, 0, 0);
            }
        }

        // ---------- phase 1c: write fp32 partials ----------
        {
            int colj  = ct * 16 + (lane & 15);
            int rowb0 = (lane >> 4) * 4;
            #pragma unroll
            for (int m = 0; m < 4; ++m) {
                size_t pb = ((size_t)kp * Bb + m * 16 + rowb0) * Hh + colj;
                #pragma unroll
                for (int q = 0; q < 4; ++q) {
                    Pz[pb + (size_t)q * Hh] = accZ[m][q];
                    Pr[pb + (size_t)q * Hh] = accR[m][q];
                    Pn[pb + (size_t)q * Hh] = accN[m][q];
                }
            }
        }
        grid_barrier(bar, 2 * t, gid, tid);

        // ---------- phase 2: reduce partials, gates, update h ----------
        #pragma unroll
        for (int q = 0; q < 2; ++q) if (vv[q]) {
            int e = ee[q];
            size_t o = (size_t)(e >> 10) * Hh + (e & (Hh - 1));
            float zs = 0.f, rs = 0.f, us = 0.f, vs = 0.f;
            #pragma unroll
            for (int kk = 0; kk < KP_TOT; ++kk) {
                size_t po = (size_t)kk * (Bb * Hh) + o;
                zs += Pz[po];
                rs += Pr[po];
                float pn = Pn[po];
                if (kk < KP_X) us += pn; else vs += pn;
            }
            float z = 1.f / (1.f + __expf(-(zs + bzs[q])));
            float r = 1.f / (1.f + __expf(-(rs + brs[q])));
            float u = us + bus[q];
            float v = vs + bvs[q];
            float n = 1.f - 2.f / (__expf(2.f * (u + r * v)) + 1.f);
            float hn = (1.f - z) * n + z * hp[q];
            hp[q] = hn;
            hout[o] = f2bf(hn);
            if (t == T_STEPS - 1) out[o] = hn;
        }
        if (t != T_STEPS - 1) grid_barrier(bar, 2 * t + 1, gid, tid);
    }
}

extern "C" void kernel_launch(void* const* d_in, const int* in_sizes, int n_in,
                              void* d_out, int out_size, void* d_ws, size_t ws_size,
                              hipStream_t stream) {
    const float* x   = (const float*)d_in[0];
    const float* Wzx = (const float*)d_in[1];
    const float* Wzh = (const float*)d_in[2];
    const float* Wrx = (const float*)d_in[3];
    const float* Wrh = (const float*)d_in[4];
    const float* Wnx = (const float*)d_in[5];
    const float* Wnh = (const float*)d_in[6];
    const float* bzx = (const float*)d_in[7];
    const float* bzh = (const float*)d_in[8];
    const float* brx = (const float*)d_in[9];
    const float* brh = (const float*)d_in[10];
    const float* bnx = (const float*)d_in[11];
    const float* bnh = (const float*)d_in[12];

    unsigned char* ws = (unsigned char*)d_ws;
    unsigned*       bar = (unsigned*)ws;                         // [0, 1024)
    unsigned short* hb0 = (unsigned short*)(ws + 4096);          // 128 KB
    unsigned short* hb1 = (unsigned short*)(ws + 4096 + 131072); // 128 KB
    float* Pz = (float*)(ws + 266240);                           // 3 MB each
    float* Pr = Pz + (size_t)KP_TOT * Bb * Hh;
    float* Pn = Pr + (size_t)KP_TOT * Bb * Hh;
    unsigned short* wsw = (unsigned short*)(ws + 266240 + (size_t)3 * KP_TOT * Bb * Hh * 4);
    // total ws use ~27.3 MB

    hipMemsetAsync(bar, 0, 1024, stream);
    hipMemsetAsync(hb0, 0, (size_t)Bb * Hh * 2, stream);

    build_wsw<<<2304, 256, 0, stream>>>(Wzx, Wzh, Wrx, Wrh, Wnx, Wnh, wsw);

    gru_persist<<<NBLK, 256, 0, stream>>>(x, bzx, bzh, brx, brh, bnx, bnh,
                                          wsw, hb0, hb1, Pz, Pr, Pn, bar,
                                          (float*)d_out);
}

// Round 6
// 26966.208 us; speedup vs baseline: 5.1602x; 1.2977x over previous
//
#include <hip/hip_runtime.h>
#include <math.h>

// GRU B=64, T=512, D=512, H=1024 fp32.
// Round 5: the round-1-proven 35ms kernel (P), minimally modified:
//   KP_TOT 12 -> 6 (256-wide K chunks) halves fp32-partial traffic;
//   batch rows split in half (mh) to keep the EXACT 192-block grid and the
//   verbatim-P barrier geometry (8 groups x 24, two barriers/step).
// All correctness-bearing pieces (build_wsw, barrier, W-fetch offsets, MFMA
// fragment maps, phase-2 assignment, double-buffered h) are byte-identical to P.
#define T_STEPS 512
#define Bb 64
#define Dd 512
#define Hh 1024
#define NBLK 192
#define KP_X 2          // kp 0..1 = x-side (k = kp*256), kp 2..5 = h-side
#define KP_TOT 6
#define NCT 16
#define LDS_STRIDE 264  // shorts per row: 256 + 8 pad
#define EPB 342         // epilogue elements per block (192*342 >= 65536)

typedef __attribute__((ext_vector_type(8))) short short8;
typedef __attribute__((ext_vector_type(4))) short short4v;
typedef __attribute__((ext_vector_type(4))) float floatx4;

__device__ __forceinline__ unsigned short f2bf(float f) {
    unsigned u = __float_as_uint(f);
    unsigned r = u + 0x7fffu + ((u >> 16) & 1u);   // round-to-nearest-even
    return (unsigned short)(r >> 16);
}
__device__ __forceinline__ float bf2f(unsigned short h) {
    return __uint_as_float(((unsigned)h) << 16);
}

// ---------------- setup: VERBATIM round-1-proven W swizzle ----------------
// frag F = ((ct*48 + ks)*3 + g)*2 + s ; element: lane l, j ->
//   W[k = ks*32 + (l>>4)*8 + j][n = ct*16 + (l&15)]  (k<512: Wx, else Wh at k-512)
__global__ __launch_bounds__(256) void build_wsw(
    const float* __restrict__ Wzx, const float* __restrict__ Wzh,
    const float* __restrict__ Wrx, const float* __restrict__ Wrh,
    const float* __restrict__ Wnx, const float* __restrict__ Wnh,
    unsigned short* __restrict__ wsw)
{
    int idx = blockIdx.x * 256 + threadIdx.x;   // 589824 total = 2304*256
    int l = idx & 63;
    int rest = idx >> 6;
    int g = rest % 3; rest /= 3;
    int ks = rest % 48;
    int ct = rest / 48;
    if (ct >= 64) return;
    int k0 = ks * 32 + ((l >> 4) << 3);
    int n  = ct * 16 + (l & 15);
    const float* Wx = (g == 0) ? Wzx : (g == 1) ? Wrx : Wnx;
    const float* Wh = (g == 0) ? Wzh : (g == 1) ? Wrh : Wnh;
    const float* src = (k0 < Dd) ? (Wx + (size_t)k0 * Hh + n)
                                 : (Wh + (size_t)(k0 - Dd) * Hh + n);
    size_t base = ((((size_t)ct * 48 + ks) * 3 + g) * 2) * 512;
    unsigned short* hi = wsw + base + l * 8;
    unsigned short* lo = hi + 512;
    #pragma unroll
    for (int j = 0; j < 8; ++j) {
        float w = src[(size_t)j * Hh];
        unsigned short h16 = f2bf(w);
        hi[j] = h16;
        lo[j] = f2bf(w - bf2f(h16));
    }
}

// ---------------- VERBATIM round-1-proven grid barrier (8 groups x 24) -----------
__device__ __forceinline__ void grid_barrier(unsigned* bar, int phase, int gid, int tid) {
    __syncthreads();
    if (tid == 0) {
        __threadfence();   // device-scope release of this block's stores
        unsigned old = __hip_atomic_fetch_add(&bar[gid * 16], 1u,
                                              __ATOMIC_ACQ_REL, __HIP_MEMORY_SCOPE_AGENT);
        if (old == (unsigned)(phase * 24 + 23)) {            // last arriver in group
            unsigned m = __hip_atomic_fetch_add(&bar[128], 1u,
                                                __ATOMIC_ACQ_REL, __HIP_MEMORY_SCOPE_AGENT);
            if (m == (unsigned)(phase * 8 + 7)) {            // last group
                __hip_atomic_fetch_add(&bar[144], 1u,
                                       __ATOMIC_RELEASE, __HIP_MEMORY_SCOPE_AGENT);
            }
        }
        while (__hip_atomic_load(&bar[144], __ATOMIC_ACQUIRE,
                                 __HIP_MEMORY_SCOPE_AGENT) < (unsigned)(phase + 1)) {
            __builtin_amdgcn_s_sleep(2);
        }
    }
    __syncthreads();
}

// ---------------- persistent GRU kernel ----------------
__global__ __launch_bounds__(256) void gru_persist(
    const float* __restrict__ x,
    const float* __restrict__ bzx, const float* __restrict__ bzh,
    const float* __restrict__ brx, const float* __restrict__ brh,
    const float* __restrict__ bnx, const float* __restrict__ bnh,
    const unsigned short* __restrict__ wsw,
    unsigned short* __restrict__ hb0, unsigned short* __restrict__ hb1,
    float* __restrict__ Pz, float* __restrict__ Pr, float* __restrict__ Pn,
    unsigned* __restrict__ bar,
    float* __restrict__ out)
{
    __shared__ unsigned short lds_a[32 * LDS_STRIDE];   // 32 rows x 264 shorts = 16.9 KB

    const int tid  = threadIdx.x;
    const int lane = tid & 63;
    const int wave = tid >> 6;
    const int kp   = blockIdx.x >> 5;          // 0..5 (K partition, 256 wide)
    const int rem  = blockIdx.x & 31;
    const int mh   = rem >> 4;                 // 0..1 (batch half: rows mh*32..+32)
    const int ct4  = rem & 15;                 // 0..15
    const int ct   = ct4 * 4 + wave;           // 16-col tile per wave
    const int gid  = blockIdx.x / 24;          // barrier group (verbatim P)
    const int R0   = mh * 32;                  // first batch row of this block

    // ---- fixed epilogue assignment: VERBATIM P ----
    const int e_base = blockIdx.x * EPB;
    int  ee[2];  bool vv[2];
    ee[0] = e_base + tid;         vv[0] = (ee[0] < Bb * Hh);
    ee[1] = e_base + 256 + tid;   vv[1] = (tid < EPB - 256) && (ee[1] < Bb * Hh);
    float bzs[2], brs[2], bus[2], bvs[2], hp[2];
    #pragma unroll
    for (int q = 0; q < 2; ++q) {
        bzs[q] = brs[q] = bus[q] = bvs[q] = 0.f; hp[q] = 0.f;
        if (vv[q]) {
            int j = ee[q] & (Hh - 1);
            bzs[q] = bzx[j] + bzh[j];
            brs[q] = brx[j] + brh[j];
            bus[q] = bnx[j];
            bvs[q] = bnh[j];
        }
    }

    // W fragment base: global ks index = kp*8 + ks, F = ((ct*48 + kp*8 + ks)*3+g)*2+s
    const size_t wbase = (((size_t)ct * 48 + kp * 8) * 3) * 2 * 512 + (size_t)lane * 8;

    for (int t = 0; t < T_STEPS; ++t) {
        const unsigned short* hin  = (t & 1) ? hb1 : hb0;
        unsigned short*       hout = (t & 1) ? hb0 : hb1;

        // ---------- phase 1a: stage A slice [32 rows x 256 k] into LDS ----------
        if (kp < KP_X) {
            // x fp32 -> bf16: 8192 elems = 2048 float4 chunks, 8 passes x 256 thr
            #pragma unroll
            for (int i = 0; i < 8; ++i) {
                int f   = i * 256 + tid;
                int row = f >> 6;                 // 0..31
                int c4  = (f & 63) << 2;          // 0..252
                float4 v = *(const float4*)(x + ((size_t)(R0 + row) * T_STEPS + t) * Dd
                                            + kp * 256 + c4);
                short4v s;
                s.x = (short)f2bf(v.x); s.y = (short)f2bf(v.y);
                s.z = (short)f2bf(v.z); s.w = (short)f2bf(v.w);
                *(short4v*)&lds_a[row * LDS_STRIDE + c4] = s;
            }
        } else {
            // h bf16: 8192 elems = 1024 short8 chunks, 4 passes x 256 thr
            #pragma unroll
            for (int i = 0; i < 4; ++i) {
                int f   = i * 256 + tid;
                int row = f >> 5;                 // 0..31
                int c8  = (f & 31) << 3;          // 0..248
                short8 v8 = *(const short8*)(hin + (size_t)(R0 + row) * Hh
                                             + (kp - KP_X) * 256 + c8);
                *(short8*)&lds_a[row * LDS_STRIDE + c8] = v8;
            }
        }
        __syncthreads();

        // ---------- phase 1b: MFMA partial GEMM (W streamed, split hi+lo) ----------
        floatx4 zero4 = {0.f, 0.f, 0.f, 0.f};
        floatx4 accZ[2] = {zero4, zero4};
        floatx4 accR[2] = {zero4, zero4};
        floatx4 accN[2] = {zero4, zero4};
        #pragma unroll
        for (int ks = 0; ks < 8; ++ks) {
            const unsigned short* wp = wsw + wbase + (size_t)ks * 3072;
            short8 bzh8 = *(const short8*)(wp);
            short8 bzl8 = *(const short8*)(wp + 512);
            short8 brh8 = *(const short8*)(wp + 1024);
            short8 brl8 = *(const short8*)(wp + 1536);
            short8 bnh8 = *(const short8*)(wp + 2048);
            short8 bnl8 = *(const short8*)(wp + 2560);
            #pragma unroll
            for (int m = 0; m < 2; ++m) {
                const short8 a = *(const short8*)&lds_a[(m * 16 + (lane & 15)) * LDS_STRIDE
                                                        + ks * 32 + ((lane >> 4) << 3)];
                accZ[m] = __builtin_amdgcn_mfma_f32_16x16x32_bf16(a, bzh8, accZ[m], 0, 0, 0);
                accZ[m] = __builtin_amdgcn_mfma_f32_16x16x32_bf16(a, bzl8, accZ[m], 0, 0, 0);
                accR[m] = __builtin_amdgcn_mfma_f32_16x16x32_bf16(a, brh8, accR[m], 0, 0, 0);
                accR[m] = __builtin_amdgcn_mfma_f32_16x16x32_bf16(a, brl8, accR[m], 0, 0, 0);
                accN[m] = __builtin_amdgcn_mfma_f32_16x16x32_bf16(a, bnh8, accN[m], 0, 0, 0);
                accN[m] = __builtin_amdgcn_mfma_f32_16x16x32_bf16(a, bnl8, accN[m], 0, 0, 0);
            }
        }

        // ---------- phase 1c: write fp32 partials ----------
        {
            int colj  = ct * 16 + (lane & 15);
            int rowb0 = (lane >> 4) * 4;
            #pragma unroll
            for (int m = 0; m < 2; ++m) {
                size_t pb = ((size_t)kp * Bb + R0 + m * 16 + rowb0) * Hh + colj;
                #pragma unroll
                for (int q = 0; q < 4; ++q) {
                    Pz[pb + (size_t)q * Hh] = accZ[m][q];
                    Pr[pb + (size_t)q * Hh] = accR[m][q];
                    Pn[pb + (size_t)q * Hh] = accN[m][q];
                }
            }
        }
        grid_barrier(bar, 2 * t, gid, tid);

        // ---------- phase 2: reduce partials, gates, update h ----------
        #pragma unroll
        for (int q = 0; q < 2; ++q) if (vv[q]) {
            int e = ee[q];
            size_t o = (size_t)(e >> 10) * Hh + (e & (Hh - 1));
            float zs = 0.f, rs = 0.f, us = 0.f, vs = 0.f;
            #pragma unroll
            for (int kk = 0; kk < KP_TOT; ++kk) {
                size_t po = (size_t)kk * (Bb * Hh) + o;
                zs += Pz[po];
                rs += Pr[po];
                float pn = Pn[po];
                if (kk < KP_X) us += pn; else vs += pn;
            }
            float z = 1.f / (1.f + __expf(-(zs + bzs[q])));
            float r = 1.f / (1.f + __expf(-(rs + brs[q])));
            float u = us + bus[q];
            float v = vs + bvs[q];
            float n = 1.f - 2.f / (__expf(2.f * (u + r * v)) + 1.f);
            float hn = (1.f - z) * n + z * hp[q];
            hp[q] = hn;
            hout[o] = f2bf(hn);
            if (t == T_STEPS - 1) out[o] = hn;
        }
        if (t != T_STEPS - 1) grid_barrier(bar, 2 * t + 1, gid, tid);
    }
}

extern "C" void kernel_launch(void* const* d_in, const int* in_sizes, int n_in,
                              void* d_out, int out_size, void* d_ws, size_t ws_size,
                              hipStream_t stream) {
    const float* x   = (const float*)d_in[0];
    const float* Wzx = (const float*)d_in[1];
    const float* Wzh = (const float*)d_in[2];
    const float* Wrx = (const float*)d_in[3];
    const float* Wrh = (const float*)d_in[4];
    const float* Wnx = (const float*)d_in[5];
    const float* Wnh = (const float*)d_in[6];
    const float* bzx = (const float*)d_in[7];
    const float* bzh = (const float*)d_in[8];
    const float* brx = (const float*)d_in[9];
    const float* brh = (const float*)d_in[10];
    const float* bnx = (const float*)d_in[11];
    const float* bnh = (const float*)d_in[12];

    unsigned char* ws = (unsigned char*)d_ws;
    unsigned*       bar = (unsigned*)ws;                         // [0, 1024)
    unsigned short* hb0 = (unsigned short*)(ws + 4096);          // 128 KB
    unsigned short* hb1 = (unsigned short*)(ws + 4096 + 131072); // 128 KB
    float* Pz = (float*)(ws + 266240);                           // 1.5 MB each
    float* Pr = Pz + (size_t)KP_TOT * Bb * Hh;
    float* Pn = Pr + (size_t)KP_TOT * Bb * Hh;
    unsigned short* wsw = (unsigned short*)(ws + 266240 + (size_t)3 * KP_TOT * Bb * Hh * 4);
    // total ws use ~23.9 MB (round-1 used 27.3 MB successfully)

    hipMemsetAsync(bar, 0, 1024, stream);
    hipMemsetAsync(hb0, 0, (size_t)Bb * Hh * 2, stream);

    build_wsw<<<2304, 256, 0, stream>>>(Wzx, Wzh, Wrx, Wrh, Wnx, Wnh, wsw);

    gru_persist<<<NBLK, 256, 0, stream>>>(x, bzx, bzh, brx, brh, bnx, bnh,
                                          wsw, hb0, hb1, Pz, Pr, Pn, bar,
                                          (float*)d_out);
}

// Round 7
// 19927.431 us; speedup vs baseline: 6.9829x; 1.3532x over previous
//
#include <hip/hip_runtime.h>
#include <math.h>

// GRU B=64, T=512, D=512, H=1024 fp32.
// Round 6: ONE grid barrier per step (was 2). h never round-trips global memory:
//   each h-side block reduces exactly the partials it needs for its next-step
//   A-tile, keeps h_prev in registers, writes h directly into LDS (fragment
//   layout). x-side blocks are decoupled (no h dependency). Partials parity-
//   double-buffered; the single barrier separates cross-parity access.
// 96 blocks = (6 kp) x (2 mh) x (8 cg); per wave 2 ct-tiles x 2 m x 8 ks.
// build_wsw / barrier structure / MFMA maps / staging layouts verbatim R5-proven.
#define T_STEPS 512
#define Bb 64
#define Dd 512
#define Hh 1024
#define NBLK 96
#define KP_X 2          // kp 0..1 = x-side (256-wide), kp 2..5 = h-side (256-wide)
#define KP_TOT 6
#define GRP 12          // blocks per barrier group (8 groups x 12 = 96)
#define LDS_STRIDE 264  // shorts per row: 256 + 8 pad
#define PPAR (KP_TOT * Bb * Hh)   // floats per parity per gate array (393216)

typedef __attribute__((ext_vector_type(8))) short short8;
typedef __attribute__((ext_vector_type(4))) short short4v;
typedef __attribute__((ext_vector_type(4))) float floatx4;

__device__ __forceinline__ unsigned short f2bf(float f) {
    unsigned u = __float_as_uint(f);
    unsigned r = u + 0x7fffu + ((u >> 16) & 1u);   // RNE
    return (unsigned short)(r >> 16);
}
__device__ __forceinline__ float bf2f(unsigned short h) {
    return __uint_as_float(((unsigned)h) << 16);
}
__device__ __forceinline__ float gru_h(float zs, float rs, float us, float vs,
                                       float bz, float br, float bu, float bv,
                                       float hprev) {
    float z = 1.f / (1.f + __expf(-(zs + bz)));
    float r = 1.f / (1.f + __expf(-(rs + br)));
    float n = 1.f - 2.f / (__expf(2.f * (us + bu + r * (vs + bv))) + 1.f);
    return (1.f - z) * n + z * hprev;
}

// ---------------- setup: VERBATIM round-1-proven W swizzle ----------------
// frag F = ((ct*48 + ks)*3 + g)*2 + s ; element: lane l, j ->
//   W[k = ks*32 + (l>>4)*8 + j][n = ct*16 + (l&15)]  (k<512: Wx, else Wh at k-512)
__global__ __launch_bounds__(256) void build_wsw(
    const float* __restrict__ Wzx, const float* __restrict__ Wzh,
    const float* __restrict__ Wrx, const float* __restrict__ Wrh,
    const float* __restrict__ Wnx, const float* __restrict__ Wnh,
    unsigned short* __restrict__ wsw)
{
    int idx = blockIdx.x * 256 + threadIdx.x;   // 589824 total = 2304*256
    int l = idx & 63;
    int rest = idx >> 6;
    int g = rest % 3; rest /= 3;
    int ks = rest % 48;
    int ct = rest / 48;
    if (ct >= 64) return;
    int k0 = ks * 32 + ((l >> 4) << 3);
    int n  = ct * 16 + (l & 15);
    const float* Wx = (g == 0) ? Wzx : (g == 1) ? Wrx : Wnx;
    const float* Wh = (g == 0) ? Wzh : (g == 1) ? Wrh : Wnh;
    const float* src = (k0 < Dd) ? (Wx + (size_t)k0 * Hh + n)
                                 : (Wh + (size_t)(k0 - Dd) * Hh + n);
    size_t base = ((((size_t)ct * 48 + ks) * 3 + g) * 2) * 512;
    unsigned short* hi = wsw + base + l * 8;
    unsigned short* lo = hi + 512;
    #pragma unroll
    for (int j = 0; j < 8; ++j) {
        float w = src[(size_t)j * Hh];
        unsigned short h16 = f2bf(w);
        hi[j] = h16;
        lo[j] = f2bf(w - bf2f(h16));
    }
}

// ---------------- grid barrier: proven structure, 8 groups x GRP ----------------
__device__ __forceinline__ void grid_barrier(unsigned* bar, int phase, int gid, int tid) {
    __syncthreads();
    if (tid == 0) {
        __threadfence();   // device-scope release of this block's stores
        unsigned old = __hip_atomic_fetch_add(&bar[gid * 16], 1u,
                                              __ATOMIC_ACQ_REL, __HIP_MEMORY_SCOPE_AGENT);
        if (old == (unsigned)(phase * GRP + (GRP - 1))) {    // last arriver in group
            unsigned m = __hip_atomic_fetch_add(&bar[128], 1u,
                                                __ATOMIC_ACQ_REL, __HIP_MEMORY_SCOPE_AGENT);
            if (m == (unsigned)(phase * 8 + 7)) {            // last group
                __hip_atomic_fetch_add(&bar[144], 1u,
                                       __ATOMIC_RELEASE, __HIP_MEMORY_SCOPE_AGENT);
            }
        }
        while (__hip_atomic_load(&bar[144], __ATOMIC_ACQUIRE,
                                 __HIP_MEMORY_SCOPE_AGENT) < (unsigned)(phase + 1)) {
            __builtin_amdgcn_s_sleep(2);
        }
    }
    __syncthreads();
}

// ---------------- persistent GRU kernel ----------------
__global__ __launch_bounds__(256) void gru_persist(
    const float* __restrict__ x,
    const float* __restrict__ bzx, const float* __restrict__ bzh,
    const float* __restrict__ brx, const float* __restrict__ brh,
    const float* __restrict__ bnx, const float* __restrict__ bnh,
    const unsigned short* __restrict__ wsw,
    float* __restrict__ Pz, float* __restrict__ Pr, float* __restrict__ Pn,
    unsigned* __restrict__ bar,
    float* __restrict__ out)
{
    __shared__ unsigned short lds_a[32 * LDS_STRIDE];   // 16.9 KB

    const int tid  = threadIdx.x;
    const int lane = tid & 63;
    const int wave = tid >> 6;
    const int kp   = blockIdx.x >> 4;          // 0..5
    const int rem  = blockIdx.x & 15;
    const int mh   = rem >> 3;                 // 0..1: rows mh*32..+32
    const int cg   = rem & 7;                  // 0..7: col group
    const int gid  = blockIdx.x / GRP;         // 8 barrier groups
    const int R0   = mh * 32;
    const int ct0  = cg * 8 + wave * 2;        // this wave's two 16-col tiles

    // ---- reduce ownership (h-blocks only): rows R0+p*4+r4, cols jglob..+4 ----
    const int r4    = tid >> 6;                // == wave
    const int jloc  = (tid & 63) * 4;          // 0..252, local k within 256-slice
    const int jglob = (kp - KP_X) * 256 + jloc;

    float hp[8][4];
    floatx4 bz4, br4, bu4, bv4;
    if (kp >= KP_X) {
        #pragma unroll
        for (int p = 0; p < 8; ++p)
            #pragma unroll
            for (int c = 0; c < 4; ++c) hp[p][c] = 0.f;
        #pragma unroll
        for (int c = 0; c < 4; ++c) {
            int j = jglob + c;
            bz4[c] = bzx[j] + bzh[j];
            br4[c] = brx[j] + brh[j];
            bu4[c] = bnx[j];        // bias OUTSIDE r-gate (x-side of n)
            bv4[c] = bnh[j];        // bias INSIDE  r-gate (h-side of n)
        }
    }

    const size_t wb0 = (((size_t)ct0       * 48 + kp * 8) * 3) * 2 * 512 + (size_t)lane * 8;
    const size_t wb1 = (((size_t)(ct0 + 1) * 48 + kp * 8) * 3) * 2 * 512 + (size_t)lane * 8;

    for (int t = 0; t < T_STEPS; ++t) {
        // ---------- phase A: build A-tile [32 rows x 256 k] in LDS ----------
        if (kp < KP_X) {
            // x fp32 -> bf16 (verbatim R5 x-branch)
            #pragma unroll
            for (int i = 0; i < 8; ++i) {
                int f   = i * 256 + tid;
                int row = f >> 6;
                int c4  = (f & 63) << 2;
                float4 v = *(const float4*)(x + ((size_t)(R0 + row) * T_STEPS + t) * Dd
                                            + kp * 256 + c4);
                short4v s;
                s.x = (short)f2bf(v.x); s.y = (short)f2bf(v.y);
                s.z = (short)f2bf(v.z); s.w = (short)f2bf(v.w);
                *(short4v*)&lds_a[row * LDS_STRIDE + c4] = s;
            }
        } else if (t == 0) {
            short4v zz = {0, 0, 0, 0};
            #pragma unroll
            for (int p = 0; p < 8; ++p)
                *(short4v*)&lds_a[(p * 4 + r4) * LDS_STRIDE + jloc] = zz;
        } else {
            // reduce P[(t-1)&1] -> h(t) for exactly this block's A-tile
            const float* Pzr = Pz + (size_t)((t - 1) & 1) * PPAR;
            const float* Prr = Pr + (size_t)((t - 1) & 1) * PPAR;
            const float* Pnr = Pn + (size_t)((t - 1) & 1) * PPAR;
            #pragma unroll
            for (int p = 0; p < 8; ++p) {
                size_t o = (size_t)(R0 + p * 4 + r4) * Hh + jglob;
                floatx4 zs = {0.f,0.f,0.f,0.f}, rs = zs, us = zs, vs = zs;
                #pragma unroll
                for (int kk = 0; kk < KP_TOT; ++kk) {
                    size_t po = (size_t)kk * (Bb * Hh) + o;
                    floatx4 pz = *(const floatx4*)(Pzr + po);
                    floatx4 pr = *(const floatx4*)(Prr + po);
                    floatx4 pn = *(const floatx4*)(Pnr + po);
                    zs += pz; rs += pr;
                    if (kk < KP_X) us += pn; else vs += pn;
                }
                short4v hv;
                #pragma unroll
                for (int c = 0; c < 4; ++c) {
                    float hn = gru_h(zs[c], rs[c], us[c], vs[c],
                                     bz4[c], br4[c], bu4[c], bv4[c], hp[p][c]);
                    hp[p][c] = hn;
                    hv[c] = (short)f2bf(hn);
                }
                *(short4v*)&lds_a[(p * 4 + r4) * LDS_STRIDE + jloc] = hv;
            }
        }
        __syncthreads();

        // ---------- phase B: MFMA (W streamed hi+lo, verbatim R5 maps) ----------
        floatx4 zero4 = {0.f, 0.f, 0.f, 0.f};
        floatx4 accZ[2][2] = {{zero4, zero4}, {zero4, zero4}};
        floatx4 accR[2][2] = {{zero4, zero4}, {zero4, zero4}};
        floatx4 accN[2][2] = {{zero4, zero4}, {zero4, zero4}};
        #pragma unroll
        for (int ks = 0; ks < 8; ++ks) {
            const short8 a0 = *(const short8*)&lds_a[(lane & 15) * LDS_STRIDE
                                                     + ks * 32 + ((lane >> 4) << 3)];
            const short8 a1 = *(const short8*)&lds_a[(16 + (lane & 15)) * LDS_STRIDE
                                                     + ks * 32 + ((lane >> 4) << 3)];
            #pragma unroll
            for (int u = 0; u < 2; ++u) {
                const unsigned short* wp = wsw + (u ? wb1 : wb0) + (size_t)ks * 3072;
                short8 zh8 = *(const short8*)(wp);
                short8 zl8 = *(const short8*)(wp + 512);
                short8 rh8 = *(const short8*)(wp + 1024);
                short8 rl8 = *(const short8*)(wp + 1536);
                short8 nh8 = *(const short8*)(wp + 2048);
                short8 nl8 = *(const short8*)(wp + 2560);
                accZ[u][0] = __builtin_amdgcn_mfma_f32_16x16x32_bf16(a0, zh8, accZ[u][0], 0, 0, 0);
                accZ[u][0] = __builtin_amdgcn_mfma_f32_16x16x32_bf16(a0, zl8, accZ[u][0], 0, 0, 0);
                accR[u][0] = __builtin_amdgcn_mfma_f32_16x16x32_bf16(a0, rh8, accR[u][0], 0, 0, 0);
                accR[u][0] = __builtin_amdgcn_mfma_f32_16x16x32_bf16(a0, rl8, accR[u][0], 0, 0, 0);
                accN[u][0] = __builtin_amdgcn_mfma_f32_16x16x32_bf16(a0, nh8, accN[u][0], 0, 0, 0);
                accN[u][0] = __builtin_amdgcn_mfma_f32_16x16x32_bf16(a0, nl8, accN[u][0], 0, 0, 0);
                accZ[u][1] = __builtin_amdgcn_mfma_f32_16x16x32_bf16(a1, zh8, accZ[u][1], 0, 0, 0);
                accZ[u][1] = __builtin_amdgcn_mfma_f32_16x16x32_bf16(a1, zl8, accZ[u][1], 0, 0, 0);
                accR[u][1] = __builtin_amdgcn_mfma_f32_16x16x32_bf16(a1, rh8, accR[u][1], 0, 0, 0);
                accR[u][1] = __builtin_amdgcn_mfma_f32_16x16x32_bf16(a1, rl8, accR[u][1], 0, 0, 0);
                accN[u][1] = __builtin_amdgcn_mfma_f32_16x16x32_bf16(a1, nh8, accN[u][1], 0, 0, 0);
                accN[u][1] = __builtin_amdgcn_mfma_f32_16x16x32_bf16(a1, nl8, accN[u][1], 0, 0, 0);
            }
        }

        // ---------- phase C: write fp32 partials (parity t&1) ----------
        {
            float* Pzw = Pz + (size_t)(t & 1) * PPAR;
            float* Prw = Pr + (size_t)(t & 1) * PPAR;
            float* Pnw = Pn + (size_t)(t & 1) * PPAR;
            int colj  = lane & 15;
            int rowb0 = (lane >> 4) * 4;
            #pragma unroll
            for (int u = 0; u < 2; ++u) {
                #pragma unroll
                for (int m = 0; m < 2; ++m) {
                    size_t pb = ((size_t)kp * Bb + R0 + m * 16 + rowb0) * Hh
                                + (ct0 + u) * 16 + colj;
                    #pragma unroll
                    for (int q = 0; q < 4; ++q) {
                        Pzw[pb + (size_t)q * Hh] = accZ[u][m][q];
                        Prw[pb + (size_t)q * Hh] = accR[u][m][q];
                        Pnw[pb + (size_t)q * Hh] = accN[u][m][q];
                    }
                }
            }
        }
        grid_barrier(bar, t, gid, tid);
    }

    // ---------- final: h-blocks reduce P[(T-1)&1] -> out (fp32) ----------
    if (kp >= KP_X) {
        const float* Pzr = Pz + (size_t)((T_STEPS - 1) & 1) * PPAR;
        const float* Prr = Pr + (size_t)((T_STEPS - 1) & 1) * PPAR;
        const float* Pnr = Pn + (size_t)((T_STEPS - 1) & 1) * PPAR;
        #pragma unroll
        for (int p = 0; p < 8; ++p) {
            size_t o = (size_t)(R0 + p * 4 + r4) * Hh + jglob;
            floatx4 zs = {0.f,0.f,0.f,0.f}, rs = zs, us = zs, vs = zs;
            #pragma unroll
            for (int kk = 0; kk < KP_TOT; ++kk) {
                size_t po = (size_t)kk * (Bb * Hh) + o;
                floatx4 pz = *(const floatx4*)(Pzr + po);
                floatx4 pr = *(const floatx4*)(Prr + po);
                floatx4 pn = *(const floatx4*)(Pnr + po);
                zs += pz; rs += pr;
                if (kk < KP_X) us += pn; else vs += pn;
            }
            floatx4 hv;
            #pragma unroll
            for (int c = 0; c < 4; ++c)
                hv[c] = gru_h(zs[c], rs[c], us[c], vs[c],
                              bz4[c], br4[c], bu4[c], bv4[c], hp[p][c]);
            *(floatx4*)(out + o) = hv;
        }
    }
}

extern "C" void kernel_launch(void* const* d_in, const int* in_sizes, int n_in,
                              void* d_out, int out_size, void* d_ws, size_t ws_size,
                              hipStream_t stream) {
    const float* x   = (const float*)d_in[0];
    const float* Wzx = (const float*)d_in[1];
    const float* Wzh = (const float*)d_in[2];
    const float* Wrx = (const float*)d_in[3];
    const float* Wrh = (const float*)d_in[4];
    const float* Wnx = (const float*)d_in[5];
    const float* Wnh = (const float*)d_in[6];
    const float* bzx = (const float*)d_in[7];
    const float* bzh = (const float*)d_in[8];
    const float* brx = (const float*)d_in[9];
    const float* brh = (const float*)d_in[10];
    const float* bnx = (const float*)d_in[11];
    const float* bnh = (const float*)d_in[12];

    unsigned char* ws = (unsigned char*)d_ws;
    unsigned* bar = (unsigned*)ws;                       // 4 KB
    float* Pz = (float*)(ws + 4096);                     // 2 parities x 1.5 MB
    float* Pr = Pz + 2 * (size_t)PPAR;
    float* Pn = Pr + 2 * (size_t)PPAR;
    unsigned short* wsw = (unsigned short*)(ws + 4096 + (size_t)6 * PPAR * 4);
    // total ws use ~28.3 MB

    hipMemsetAsync(bar, 0, 4096, stream);

    build_wsw<<<2304, 256, 0, stream>>>(Wzx, Wzh, Wrx, Wrh, Wnx, Wnh, wsw);

    gru_persist<<<NBLK, 256, 0, stream>>>(x, bzx, bzh, brx, brh, bnx, bnh,
                                          wsw, Pz, Pr, Pn, bar, (float*)d_out);
}